// Round 7
// baseline (1447.678 us; speedup 1.0000x reference)
//
#include <hip/hip_runtime.h>

#define BB 512
#define TT 512
#define FF 64
#define HH 128
#define G4 512
#define NCLS 10
#define CH 4             // out1 flush chunk (steps)
#define NCH (TT / CH)    // 128 chunks
#define HBP 136          // padded h row (shorts)
#define HBSZ (16 * HBP)  // one hb buffer (shorts)

typedef __attribute__((ext_vector_type(8))) short short8;
typedef __attribute__((ext_vector_type(4))) float f32x4;

__device__ __forceinline__ float sigf(float x) { return 1.0f / (1.0f + __expf(-x)); }
__device__ __forceinline__ float tanhfast(float x) { return 2.0f / (1.0f + __expf(-2.0f * x)) - 1.0f; }
__device__ __forceinline__ unsigned short f2bf(float f) {
    union { float f; unsigned u; } v; v.f = f;
    unsigned r = v.u + 0x7FFFu + ((v.u >> 16) & 1u);   // RNE
    return (unsigned short)(r >> 16);
}

__device__ __forceinline__ void wait_flag(int* f) {
    if (threadIdx.x == 0) {
        while (__hip_atomic_load(f, __ATOMIC_ACQUIRE, __HIP_MEMORY_SCOPE_AGENT) == 0)
            __builtin_amdgcn_s_sleep(2);
    }
    __syncthreads();
    (void)__hip_atomic_load(f, __ATOMIC_ACQUIRE, __HIP_MEMORY_SCOPE_AGENT);
}
__device__ __forceinline__ void set_flag(int* f) {   // also acts as the phase barrier
    __threadfence();
    __syncthreads();
    if (threadIdx.x == 0)
        __hip_atomic_fetch_add(f, 1, __ATOMIC_RELEASE, __HIP_MEMORY_SCOPE_AGENT);
}

// ---------------------------------------------------------------------------
// One LSTM layer scan. Block = 16 batch rows, 512 threads = 8 waves.
// Wave w owns gate tiles {w, w+8, w+16, w+24} -> lane (w,kb,lm) holds
// i,f,g,o of unit u = w*16+lm for rows kb*4+r : in-lane epilogue.
// Phase p: gates(p) = acc_pre(p) [bias + x-part, computed in phase p-1]
//          + h(p-1) @ W_hh^T  (4 MFMAs per gate tile).
// No global op pends across a barrier: window loads issue at phase start and
// commit to LDS at phase end; out1 stores are bulk per CH-step chunk issued
// at phase start; flags released 2 phases after their stores.
// ---------------------------------------------------------------------------
template<int XW, bool IS_L1>
__device__ void layer_scan(
    const void* __restrict__ xin_,
    const float* __restrict__ w_ih, const float* __restrict__ w_hh,
    const float* __restrict__ b_ih, const float* __restrict__ b_hh,
    unsigned short* __restrict__ out1, float* __restrict__ h2s,
    int* __restrict__ f_in, int* __restrict__ f_out,
    int bg, unsigned short* smem)
{
    const int tid = threadIdx.x;
    const int w = tid >> 6, l = tid & 63, lm = l & 15, kb = l >> 4;
    const int u = w * 16 + lm;
    constexpr int KTX = XW / 32;           // 2 (L1) / 4 (L2)
    constexpr int XWP = XW + 8;            // padded window row (shorts)
    constexpr int XB  = 4 * 16 * XWP;      // one window buffer (shorts)
    constexpr int OBS = 16 * CH * HH;      // one obuf buffer (shorts)

    unsigned short* xw = smem;                      // 2 windows
    unsigned short* hb = smem + 2 * XB;             // 2 h buffers
    unsigned short* ob = smem + 2 * XB + 2 * HBSZ;  // 2 obuf buffers (L1)

    // --- stationary weights (bf16) + bias ---
    short8 bfx[4][KTX], bfh[4][4];
    float bv[4];
    #pragma unroll
    for (int j = 0; j < 4; j++) {
        const int g = j * 128 + u;
        bv[j] = b_ih[g] + b_hh[g];
        #pragma unroll
        for (int kt = 0; kt < KTX; kt++) {
            const float* s = w_ih + (size_t)g * XW + kt * 32 + kb * 8;
            short8 t;
            #pragma unroll
            for (int q = 0; q < 8; q++) t[q] = (short)f2bf(s[q]);
            bfx[j][kt] = t;
        }
        #pragma unroll
        for (int kt = 0; kt < 4; kt++) {
            const float* s = w_hh + (size_t)g * HH + kt * 32 + kb * 8;
            short8 t;
            #pragma unroll
            for (int q = 0; q < 8; q++) t[q] = (short)f2bf(s[q]);
            bfh[j][kt] = t;
        }
    }

    for (int i = tid; i < 2 * HBSZ; i += 512) hb[i] = 0;

    // --- prologue: stage window 0 (steps 0..3) ---
    if (!IS_L1) wait_flag(&f_in[0]);
    if (IS_L1) {
        const float* x = (const float*)xin_;
        const int flat = tid * 8;
        const int tt = flat >> 10, row = (flat >> 6) & 15, k = flat & 63;
        const float* s = x + (((size_t)(bg * 16 + row)) * TT + tt) * FF + k;
        const float4 a = *(const float4*)s, b = *(const float4*)(s + 4);
        uint4 pv;
        pv.x = (unsigned)f2bf(a.x) | ((unsigned)f2bf(a.y) << 16);
        pv.y = (unsigned)f2bf(a.z) | ((unsigned)f2bf(a.w) << 16);
        pv.z = (unsigned)f2bf(b.x) | ((unsigned)f2bf(b.y) << 16);
        pv.w = (unsigned)f2bf(b.z) | ((unsigned)f2bf(b.w) << 16);
        *(uint4*)&xw[(tt * 16 + row) * XWP + k] = pv;
    } else {
        const unsigned short* o1 = (const unsigned short*)xin_;
        const int flat = tid * 16;
        const int tt = flat >> 11, row = (flat >> 7) & 15, k = flat & 127;
        const unsigned short* s = o1 + (((size_t)(bg * 16 + row)) * TT + tt) * HH + k;
        *(uint4*)&xw[(tt * 16 + row) * XWP + k]     = *(const uint4*)s;
        *(uint4*)&xw[(tt * 16 + row) * XWP + k + 8] = *(const uint4*)(s + 8);
    }
    __syncthreads();

    // --- acc_pre for step 0 ---
    f32x4 ap0 = {bv[0], bv[0], bv[0], bv[0]};
    f32x4 ap1 = {bv[1], bv[1], bv[1], bv[1]};
    f32x4 ap2 = {bv[2], bv[2], bv[2], bv[2]};
    f32x4 ap3 = {bv[3], bv[3], bv[3], bv[3]};
    {
        const unsigned short* ax = xw + lm * XWP + kb * 8;   // window 0, step 0
        #pragma unroll
        for (int kt = 0; kt < KTX; kt++) {
            const short8 a = *(const short8*)(ax + kt * 32);
            ap0 = __builtin_amdgcn_mfma_f32_16x16x32_bf16(a, bfx[0][kt], ap0, 0, 0, 0);
            ap1 = __builtin_amdgcn_mfma_f32_16x16x32_bf16(a, bfx[1][kt], ap1, 0, 0, 0);
            ap2 = __builtin_amdgcn_mfma_f32_16x16x32_bf16(a, bfx[2][kt], ap2, 0, 0, 0);
            ap3 = __builtin_amdgcn_mfma_f32_16x16x32_bf16(a, bfx[3][kt], ap3, 0, 0, 0);
        }
    }

    float c[4] = {0.f, 0.f, 0.f, 0.f}, hl[4] = {0.f, 0.f, 0.f, 0.f};

    for (int p = 0; p < TT; p++) {
        // ---- bulk out1 flush for chunk (p>>2)-1 (global stores, issued at
        //      phase start; drained ~free by this phase's end barrier) ----
        if (IS_L1 && (p & 3) == 0 && p > 0) {
            const int cc = (p >> 2) - 1;
            const int row = tid >> 5, off = (tid & 31) * 16;
            const unsigned short* src = ob + (cc & 1) * OBS + row * (CH * HH) + off;
            unsigned short* dst = out1 + ((size_t)(bg * 16 + row) * TT + cc * CH) * HH + off;
            ((uint4*)dst)[0] = ((const uint4*)src)[0];
            ((uint4*)dst)[1] = ((const uint4*)src)[1];
        }

        // ---- staging loads for window (p+2)/4 (consumed at phase end) ----
        const bool stage = ((p & 3) == 2) && (p + 2 < TT);
        float4 pfa, pfb; uint4 q0, q1;
        if (stage) {
            if (!IS_L1) wait_flag(&f_in[(p + 2) >> 2]);
            const int t0 = p + 2;
            if (IS_L1) {
                const float* x = (const float*)xin_;
                const int flat = tid * 8;
                const int tt = flat >> 10, row = (flat >> 6) & 15, k = flat & 63;
                const float* s = x + (((size_t)(bg * 16 + row)) * TT + t0 + tt) * FF + k;
                pfa = *(const float4*)s; pfb = *(const float4*)(s + 4);
            } else {
                const unsigned short* o1 = (const unsigned short*)xin_;
                const int flat = tid * 16;
                const int tt = flat >> 11, row = (flat >> 7) & 15, k = flat & 127;
                const unsigned short* s = o1 + (((size_t)(bg * 16 + row)) * TT + t0 + tt) * HH + k;
                q0 = *(const uint4*)s; q1 = *(const uint4*)(s + 8);
            }
        }

        // ---- h-part MFMAs: gates = acc_pre + h(p-1) @ W_hh^T ----
        f32x4 a0 = ap0, a1 = ap1, a2 = ap2, a3 = ap3;
        {
            const unsigned short* ah = hb + (p & 1) * HBSZ + lm * HBP + kb * 8;
            #pragma unroll
            for (int kt = 0; kt < 4; kt++) {
                const short8 a = *(const short8*)(ah + kt * 32);
                a0 = __builtin_amdgcn_mfma_f32_16x16x32_bf16(a, bfh[0][kt], a0, 0, 0, 0);
                a1 = __builtin_amdgcn_mfma_f32_16x16x32_bf16(a, bfh[1][kt], a1, 0, 0, 0);
                a2 = __builtin_amdgcn_mfma_f32_16x16x32_bf16(a, bfh[2][kt], a2, 0, 0, 0);
                a3 = __builtin_amdgcn_mfma_f32_16x16x32_bf16(a, bfh[3][kt], a3, 0, 0, 0);
            }
        }

        // ---- in-lane epilogue: unit u, rows kb*4+r ----
        #pragma unroll
        for (int r = 0; r < 4; r++) {
            const float iv = sigf(a0[r]);
            const float fv = sigf(a1[r]);
            const float gv = tanhfast(a2[r]);
            const float ov = sigf(a3[r]);
            c[r] = fv * c[r] + iv * gv;
            const float h = ov * tanhfast(c[r]);
            hl[r] = h;
            const unsigned short h16 = f2bf(h);
            const int row = kb * 4 + r;
            hb[((p + 1) & 1) * HBSZ + row * HBP + u] = h16;
            if (IS_L1)
                ob[((p >> 2) & 1) * OBS + row * (CH * HH) + (p & 3) * HH + u] = h16;
        }

        // ---- x-part MFMAs for step p+1 ----
        if (p + 1 < TT) {
            const int s = p + 1;
            const unsigned short* ax = xw + ((s >> 2) & 1) * XB
                                     + ((s & 3) * 16 + lm) * XWP + kb * 8;
            ap0 = (f32x4){bv[0], bv[0], bv[0], bv[0]};
            ap1 = (f32x4){bv[1], bv[1], bv[1], bv[1]};
            ap2 = (f32x4){bv[2], bv[2], bv[2], bv[2]};
            ap3 = (f32x4){bv[3], bv[3], bv[3], bv[3]};
            #pragma unroll
            for (int kt = 0; kt < KTX; kt++) {
                const short8 a = *(const short8*)(ax + kt * 32);
                ap0 = __builtin_amdgcn_mfma_f32_16x16x32_bf16(a, bfx[0][kt], ap0, 0, 0, 0);
                ap1 = __builtin_amdgcn_mfma_f32_16x16x32_bf16(a, bfx[1][kt], ap1, 0, 0, 0);
                ap2 = __builtin_amdgcn_mfma_f32_16x16x32_bf16(a, bfx[2][kt], ap2, 0, 0, 0);
                ap3 = __builtin_amdgcn_mfma_f32_16x16x32_bf16(a, bfx[3][kt], ap3, 0, 0, 0);
            }
        }

        // ---- commit staged window to LDS ----
        if (stage) {
            unsigned short* buf = xw + (((p + 2) >> 2) & 1) * XB;
            if (IS_L1) {
                const int flat = tid * 8;
                const int tt = flat >> 10, row = (flat >> 6) & 15, k = flat & 63;
                uint4 pv;
                pv.x = (unsigned)f2bf(pfa.x) | ((unsigned)f2bf(pfa.y) << 16);
                pv.y = (unsigned)f2bf(pfa.z) | ((unsigned)f2bf(pfa.w) << 16);
                pv.z = (unsigned)f2bf(pfb.x) | ((unsigned)f2bf(pfb.y) << 16);
                pv.w = (unsigned)f2bf(pfb.z) | ((unsigned)f2bf(pfb.w) << 16);
                *(uint4*)&buf[(tt * 16 + row) * XWP + k] = pv;
            } else {
                const int flat = tid * 16;
                const int tt = flat >> 11, row = (flat >> 7) & 15, k = flat & 127;
                *(uint4*)&buf[(tt * 16 + row) * XWP + k]     = q0;
                *(uint4*)&buf[(tt * 16 + row) * XWP + k + 8] = q1;
            }
        }

        // ---- phase barrier / flag release (chunk c-1: its stores are 2
        //      phases old -> fence ~free) ----
        if (IS_L1 && (p & 3) == 2 && p >= 4) {
            set_flag(&f_out[(p >> 2) - 1]);
        } else {
            __syncthreads();
        }
    }

    if (IS_L1) {
        // flush + release final chunk (127)
        const int cc = NCH - 1;
        const int row = tid >> 5, off = (tid & 31) * 16;
        const unsigned short* src = ob + (cc & 1) * OBS + row * (CH * HH) + off;
        unsigned short* dst = out1 + ((size_t)(bg * 16 + row) * TT + cc * CH) * HH + off;
        ((uint4*)dst)[0] = ((const uint4*)src)[0];
        ((uint4*)dst)[1] = ((const uint4*)src)[1];
        set_flag(&f_out[cc]);
        // also release chunk 126 if not yet (p=510 released (510>>2)-1 = 126) -- done in loop
    } else {
        #pragma unroll
        for (int r = 0; r < 4; r++)
            h2s[((size_t)(bg * 16 + kb * 4 + r)) * HH + u] = hl[r];
    }
}

// bid 0-31: layer-1 (producer). bid 32-63: layer-2 (consumer).
// bid and bid+32 share bid%8 -> same XCD for out1 L2 locality.
__global__ __launch_bounds__(512, 2) void lstm_pipe(
    const float* __restrict__ x,
    const float* __restrict__ w1_ih, const float* __restrict__ w1_hh,
    const float* __restrict__ b1_ih, const float* __restrict__ b1_hh,
    const float* __restrict__ w2_ih, const float* __restrict__ w2_hh,
    const float* __restrict__ b2_ih, const float* __restrict__ b2_hh,
    unsigned short* __restrict__ out1, float* __restrict__ h2s,
    int* __restrict__ flags)
{
    // L1 layout: xw 2*4608 + hb 2*2176 + ob 2*8192 = 29952 shorts = 59904 B
    // L2 layout: xw 2*8704 + hb 2*2176             = 21760 shorts
    __shared__ __align__(16) unsigned short smem[29952];
    const int bid = blockIdx.x;
    if (bid < 32)
        layer_scan<FF, true >(x, w1_ih, w1_hh, b1_ih, b1_hh, out1, nullptr,
                              nullptr, &flags[bid * NCH], bid, smem);
    else
        layer_scan<HH, false>(out1, w2_ih, w2_hh, b2_ih, b2_hh, nullptr, h2s,
                              &flags[(bid - 32) * NCH], nullptr, bid - 32, smem);
}

__global__ void final_kernel(const float* __restrict__ h2s,
                             const float* __restrict__ w_fc,
                             const float* __restrict__ b_fc,
                             float* __restrict__ out)
{
    const int idx = blockIdx.x * blockDim.x + threadIdx.x;
    if (idx >= BB * NCLS) return;
    const int b = idx / NCLS, cls = idx % NCLS;
    const float* hp = h2s + (size_t)b * HH;
    const float* wp = w_fc + (size_t)cls * HH;
    float acc = b_fc[cls];
    #pragma unroll 8
    for (int k = 0; k < HH; k++) acc += hp[k] * wp[k];
    out[idx] = sigf(acc);
}

extern "C" void kernel_launch(void* const* d_in, const int* in_sizes, int n_in,
                              void* d_out, int out_size, void* d_ws, size_t ws_size,
                              hipStream_t stream)
{
    const float* x     = (const float*)d_in[0];
    const float* w1_ih = (const float*)d_in[1];
    const float* w1_hh = (const float*)d_in[2];
    const float* b1_ih = (const float*)d_in[3];
    const float* b1_hh = (const float*)d_in[4];
    const float* w2_ih = (const float*)d_in[5];
    const float* w2_hh = (const float*)d_in[6];
    const float* b2_ih = (const float*)d_in[7];
    const float* b2_hh = (const float*)d_in[8];
    const float* w_fc  = (const float*)d_in[9];
    const float* b_fc  = (const float*)d_in[10];
    float* out = (float*)d_out;

    // workspace: [h2s fp32 256KB | flags 16KB | out1 bf16 67MB]
    char* ws = (char*)d_ws;
    float* h2s = (float*)ws;                 ws += (size_t)BB * HH * sizeof(float);
    int* flags = (int*)ws;                   ws += 32 * NCH * sizeof(int);
    unsigned short* out1 = (unsigned short*)ws;

    hipMemsetAsync(flags, 0, 32 * NCH * sizeof(int), stream);
    lstm_pipe<<<64, 512, 0, stream>>>(x, w1_ih, w1_hh, b1_ih, b1_hh,
                                      w2_ih, w2_hh, b2_ih, b2_hh,
                                      out1, h2s, flags);
    final_kernel<<<(BB * NCLS + 255) / 256, 256, 0, stream>>>(h2s, w_fc, b_fc, out);
}

// Round 8
// 916.663 us; speedup vs baseline: 1.5793x; 1.5793x over previous
//
#include <hip/hip_runtime.h>

#define BB 512
#define TT 512
#define FF 64
#define HH 128
#define G4 512
#define NCLS 10
#define WT 4            // LDS staging window (steps)
#define CH 16           // producer->consumer chunk (steps)
#define HBP 136         // padded h row (shorts): 272 B, 16B-divisible
#define HBSZ (16 * HBP)

typedef __attribute__((ext_vector_type(8))) short short8;
typedef __attribute__((ext_vector_type(4))) float f32x4;

#define LOG2E 1.4426950408889634f

// Fast activations: raw v_exp_f32 / v_rcp_f32 (no IEEE div sequence).
__device__ __forceinline__ float sigf(float x) {
    return __builtin_amdgcn_rcpf(1.0f + __builtin_amdgcn_exp2f(-LOG2E * x));
}
__device__ __forceinline__ float tanhfast(float x) {
    return 2.0f * __builtin_amdgcn_rcpf(1.0f + __builtin_amdgcn_exp2f(-2.0f * LOG2E * x)) - 1.0f;
}
__device__ __forceinline__ unsigned short f2bf(float f) {
    union { float f; unsigned u; } v; v.f = f;
    unsigned r = v.u + 0x7FFFu + ((v.u >> 16) & 1u);   // RNE
    return (unsigned short)(r >> 16);
}

// ---- flag protocol (round-4 proven) ---------------------------------------
__device__ __forceinline__ void wait_flag(int* f) {
    if (threadIdx.x == 0) {
        while (__hip_atomic_load(f, __ATOMIC_ACQUIRE, __HIP_MEMORY_SCOPE_AGENT) == 0)
            __builtin_amdgcn_s_sleep(2);
    }
    __syncthreads();
    (void)__hip_atomic_load(f, __ATOMIC_ACQUIRE, __HIP_MEMORY_SCOPE_AGENT);
}
__device__ __forceinline__ void set_flag(int* f) {
    __threadfence();
    __syncthreads();   // doubles as the per-step barrier on chunk-end steps
    if (threadIdx.x == 0)
        __hip_atomic_fetch_add(f, 1, __ATOMIC_RELEASE, __HIP_MEMORY_SCOPE_AGENT);
}

// ---------------------------------------------------------------------------
// Fused LSTM layer scan (R6 structure). One block = 16 batch rows, 8 waves.
// Wave w owns N-tiles {w, w+8, w+16, w+24} -> lane (w,kb,lm) holds i,f,g,o of
// unit u=16w+lm for rows kb*4+r -> fully in-lane epilogue, ONE barrier/step.
// h double-buffered in LDS (read p&1, write (p+1)&1).
// ---------------------------------------------------------------------------
template<int XW, bool IS_L1>
__device__ void layer_scan(
    const void* __restrict__ xin_,
    const float* __restrict__ w_ih, const float* __restrict__ w_hh,
    const float* __restrict__ b_ih, const float* __restrict__ b_hh,
    unsigned short* __restrict__ out1,   // L1: h stream out (bf16)
    float* __restrict__ h2s,             // L2: final h out (fp32)
    int* __restrict__ f_in,              // L2: per-chunk input flags
    int* __restrict__ f_out,             // L1: per-chunk done flags
    int bg, unsigned short* xw, unsigned short* hb)
{
    const int tid = threadIdx.x;
    const int w = tid >> 6, l = tid & 63, lm = l & 15, kb = l >> 4;
    const int u = w * 16 + lm;           // owned hidden unit
    constexpr int KT  = (XW + HH) / 32;  // 6 (L1) / 8 (L2)
    constexpr int XKT = XW / 32;         // 2 / 4
    constexpr int XWP = XW + 8;          // padded LDS row (shorts)
    constexpr int XBUF = WT * 16 * XWP;  // one window buffer (shorts)

    // --- stationary B fragments + bias: gate g = j*128 + 16w + lm ---
    short8 bf[4][KT];
    float bv[4];
    #pragma unroll
    for (int j = 0; j < 4; j++) {
        const int g = j * 128 + u;
        bv[j] = b_ih[g] + b_hh[g];
        #pragma unroll
        for (int kt = 0; kt < KT; kt++) {
            const int k0 = kt * 32 + kb * 8;
            const float* s = (k0 < XW) ? (w_ih + (size_t)g * XW + k0)
                                       : (w_hh + (size_t)g * HH + (k0 - XW));
            short8 t;
            #pragma unroll
            for (int q = 0; q < 8; q++) t[q] = (short)f2bf(s[q]);
            bf[j][kt] = t;
        }
    }

    for (int i = tid; i < 2 * HBSZ; i += 512) hb[i] = 0;

    float c[4] = {0.f, 0.f, 0.f, 0.f}, hlast[4] = {0.f, 0.f, 0.f, 0.f};

    // --- prefetch window 0 into registers ---
    float4 pfa, pfb;     // L1: 8 fp32
    uint4  pf0, pf1;     // L2: 16 bf16
    if (IS_L1) {
        const float* x = (const float*)xin_;
        const int flat = tid * 8;
        const int tt = flat >> 10, row = (flat >> 6) & 15, k = flat & 63;
        const float* s = x + (((size_t)(bg * 16 + row)) * TT + tt) * FF + k;
        pfa = *(const float4*)s; pfb = *(const float4*)(s + 4);
    } else {
        wait_flag(&f_in[0]);
        const unsigned short* o1 = (const unsigned short*)xin_;
        const int flat = tid * 16;
        const int tt = flat >> 11, row = (flat >> 7) & 15, k = flat & 127;
        const unsigned short* s = o1 + (((size_t)(bg * 16 + row)) * TT + tt) * HH + k;
        pf0 = *(const uint4*)s; pf1 = *(const uint4*)(s + 8);
    }

    for (int tl = 0; tl < TT; tl++) {
        if ((tl & (WT - 1)) == 0) {
            // commit prefetched window to LDS
            unsigned short* buf = xw + ((tl >> 2) & 1) * XBUF;
            if (IS_L1) {
                const int flat = tid * 8;
                const int tt = flat >> 10, row = (flat >> 6) & 15, k = flat & 63;
                uint4 pv;
                pv.x = (unsigned)f2bf(pfa.x) | ((unsigned)f2bf(pfa.y) << 16);
                pv.y = (unsigned)f2bf(pfa.z) | ((unsigned)f2bf(pfa.w) << 16);
                pv.z = (unsigned)f2bf(pfb.x) | ((unsigned)f2bf(pfb.y) << 16);
                pv.w = (unsigned)f2bf(pfb.z) | ((unsigned)f2bf(pfb.w) << 16);
                *(uint4*)&buf[(tt * 16 + row) * XWP + k] = pv;
            } else {
                const int flat = tid * 16;
                const int tt = flat >> 11, row = (flat >> 7) & 15, k = flat & 127;
                *(uint4*)&buf[(tt * 16 + row) * XWP + k]     = pf0;
                *(uint4*)&buf[(tt * 16 + row) * XWP + k + 8] = pf1;
            }
            __syncthreads();
            // issue prefetch for next window
            const int wst = tl + WT;
            if (wst < TT) {
                if (!IS_L1 && (wst & (CH - 1)) == 0) wait_flag(&f_in[wst >> 4]);
                if (IS_L1) {
                    const float* x = (const float*)xin_;
                    const int flat = tid * 8;
                    const int tt = flat >> 10, row = (flat >> 6) & 15, k = flat & 63;
                    const float* s = x + (((size_t)(bg * 16 + row)) * TT + wst + tt) * FF + k;
                    pfa = *(const float4*)s; pfb = *(const float4*)(s + 4);
                } else {
                    const unsigned short* o1 = (const unsigned short*)xin_;
                    const int flat = tid * 16;
                    const int tt = flat >> 11, row = (flat >> 7) & 15, k = flat & 127;
                    const unsigned short* s = o1 + (((size_t)(bg * 16 + row)) * TT + wst + tt) * HH + k;
                    pf0 = *(const uint4*)s; pf1 = *(const uint4*)(s + 8);
                }
            }
        }
        const int tloc = tl & (WT - 1);
        const unsigned short* abase = xw + ((tl >> 2) & 1) * XBUF
                                    + (tloc * 16 + lm) * XWP + kb * 8;
        const unsigned short* hbase = hb + (tl & 1) * HBSZ + lm * HBP + kb * 8;

        f32x4 a0 = {bv[0], bv[0], bv[0], bv[0]};
        f32x4 a1 = {bv[1], bv[1], bv[1], bv[1]};
        f32x4 a2 = {bv[2], bv[2], bv[2], bv[2]};
        f32x4 a3 = {bv[3], bv[3], bv[3], bv[3]};
        #pragma unroll
        for (int kt = 0; kt < KT; kt++) {
            const unsigned short* ap = (kt < XKT) ? (abase + kt * 32)
                                                  : (hbase + (kt - XKT) * 32);
            const short8 a = *(const short8*)ap;
            a0 = __builtin_amdgcn_mfma_f32_16x16x32_bf16(a, bf[0][kt], a0, 0, 0, 0);
            a1 = __builtin_amdgcn_mfma_f32_16x16x32_bf16(a, bf[1][kt], a1, 0, 0, 0);
            a2 = __builtin_amdgcn_mfma_f32_16x16x32_bf16(a, bf[2][kt], a2, 0, 0, 0);
            a3 = __builtin_amdgcn_mfma_f32_16x16x32_bf16(a, bf[3][kt], a3, 0, 0, 0);
        }

        // ---- in-lane epilogue: unit u, rows kb*4+r ----
        #pragma unroll
        for (int r = 0; r < 4; r++) {
            const float iv = sigf(a0[r]);
            const float fv = sigf(a1[r]);
            const float gv = tanhfast(a2[r]);
            const float ov = sigf(a3[r]);
            c[r] = fv * c[r] + iv * gv;
            const float h = ov * tanhfast(c[r]);
            hlast[r] = h;
            const unsigned short h16 = f2bf(h);
            hb[((tl + 1) & 1) * HBSZ + (kb * 4 + r) * HBP + u] = h16;
            if (IS_L1)
                out1[(((size_t)(bg * 16 + kb * 4 + r)) * TT + tl) * HH + u] = h16;
        }

        if (IS_L1 && (tl & (CH - 1)) == (CH - 1)) {
            set_flag(&f_out[tl >> 4]);   // fence + barrier + flag
        } else {
            __syncthreads();             // publish h for next step
        }
    }

    if (!IS_L1) {
        #pragma unroll
        for (int r = 0; r < 4; r++)
            h2s[((size_t)(bg * 16 + kb * 4 + r)) * HH + u] = hlast[r];
    }
}

// bid 0-31: layer-1 scan (producer). bid 32-63: layer-2 scan (consumer).
// bid and bid+32 share bid%8 -> same XCD for out1 L2-cache locality.
__global__ __launch_bounds__(512, 1) void lstm_pipe(
    const float* __restrict__ x,
    const float* __restrict__ w1_ih, const float* __restrict__ w1_hh,
    const float* __restrict__ b1_ih, const float* __restrict__ b1_hh,
    const float* __restrict__ w2_ih, const float* __restrict__ w2_hh,
    const float* __restrict__ b2_ih, const float* __restrict__ b2_hh,
    unsigned short* __restrict__ out1, float* __restrict__ h2s,
    int* __restrict__ flags)
{
    __shared__ __align__(16) unsigned short xw[2 * WT * 16 * (HH + 8)]; // 34816 B (L2 max)
    __shared__ __align__(16) unsigned short hb[2 * HBSZ];               //  8704 B
    const int bid = blockIdx.x;
    if (bid < 32)
        layer_scan<FF, true >(x, w1_ih, w1_hh, b1_ih, b1_hh, out1, nullptr,
                              nullptr, &flags[bid * 32], bid, xw, hb);
    else
        layer_scan<HH, false>(out1, w2_ih, w2_hh, b2_ih, b2_hh, nullptr, h2s,
                              &flags[(bid - 32) * 32], nullptr, bid - 32, xw, hb);
}

__global__ void final_kernel(const float* __restrict__ h2s,
                             const float* __restrict__ w_fc,
                             const float* __restrict__ b_fc,
                             float* __restrict__ out)
{
    const int idx = blockIdx.x * blockDim.x + threadIdx.x;
    if (idx >= BB * NCLS) return;
    const int b = idx / NCLS, cls = idx % NCLS;
    const float* hp = h2s + (size_t)b * HH;
    const float* wp = w_fc + (size_t)cls * HH;
    float acc = b_fc[cls];
    #pragma unroll 8
    for (int k = 0; k < HH; k++) acc += hp[k] * wp[k];
    out[idx] = sigf(acc);
}

extern "C" void kernel_launch(void* const* d_in, const int* in_sizes, int n_in,
                              void* d_out, int out_size, void* d_ws, size_t ws_size,
                              hipStream_t stream)
{
    const float* x     = (const float*)d_in[0];
    const float* w1_ih = (const float*)d_in[1];
    const float* w1_hh = (const float*)d_in[2];
    const float* b1_ih = (const float*)d_in[3];
    const float* b1_hh = (const float*)d_in[4];
    const float* w2_ih = (const float*)d_in[5];
    const float* w2_hh = (const float*)d_in[6];
    const float* b2_ih = (const float*)d_in[7];
    const float* b2_hh = (const float*)d_in[8];
    const float* w_fc  = (const float*)d_in[9];
    const float* b_fc  = (const float*)d_in[10];
    float* out = (float*)d_out;

    // workspace: [h2s fp32 256KB | flags 4KB | out1 bf16 67MB]
    char* ws = (char*)d_ws;
    float* h2s = (float*)ws;                 ws += (size_t)BB * HH * sizeof(float);
    int* flags = (int*)ws;                   ws += 32 * 32 * sizeof(int);
    unsigned short* out1 = (unsigned short*)ws;

    hipMemsetAsync(flags, 0, 32 * 32 * sizeof(int), stream);
    lstm_pipe<<<64, 512, 0, stream>>>(x, w1_ih, w1_hh, b1_ih, b1_hh,
                                      w2_ih, w2_hh, b2_ih, b2_hh,
                                      out1, h2s, flags);
    final_kernel<<<(BB * NCLS + 255) / 256, 256, 0, stream>>>(h2s, w_fc, b_fc, out);
}